// Round 8
// baseline (1333.245 us; speedup 1.0000x reference)
//
#include <hip/hip_runtime.h>

#define H 128
#define LDP 132   // fp32 LDS row pitch for proj/node kernels
#define NN 64     // nodes per batch graph

typedef short bf8_t __attribute__((ext_vector_type(8)));   // 8 bf16 = 4 VGPRs (MFMA A/B frag)
typedef float f4_t  __attribute__((ext_vector_type(4)));   // MFMA C/D frag

__device__ __forceinline__ float silu_f(float v) {
  return v * (1.0f / (1.0f + __expf(-v)));
}
// fp32 -> bf16 (RNE), as raw ushort bits
__device__ __forceinline__ unsigned short f2bf(float f) {
  unsigned int u = __float_as_uint(f);
  u = (u + 0x7fffu + ((u >> 16) & 1u)) >> 16;
  return (unsigned short)u;
}
__device__ __forceinline__ float bf2f(unsigned short h) {
  return __uint_as_float(((unsigned int)h) << 16);
}

// ---------------- fp32 register-tiled GEMM (proj/node kernels) ----------------
template<int RPT>
__device__ __forceinline__ void gemm_acc(const float* A, const float* __restrict__ Wg,
                                         float (&acc)[RPT][8], int r0, int c0) {
#pragma unroll 4
  for (int k = 0; k < H; k += 4) {
    float4 av[RPT];
#pragma unroll
    for (int rr = 0; rr < RPT; ++rr)
      av[rr] = *(const float4*)(A + (r0 + rr) * LDP + k);
#pragma unroll
    for (int kk = 0; kk < 4; ++kk) {
      const float* wrow = Wg + (k + kk) * H + c0;
      float4 w0 = *(const float4*)(wrow);
      float4 w1 = *(const float4*)(wrow + 4);
#pragma unroll
      for (int rr = 0; rr < RPT; ++rr) {
        float a = (kk == 0) ? av[rr].x : (kk == 1) ? av[rr].y : (kk == 2) ? av[rr].z : av[rr].w;
        acc[rr][0] = fmaf(a, w0.x, acc[rr][0]);
        acc[rr][1] = fmaf(a, w0.y, acc[rr][1]);
        acc[rr][2] = fmaf(a, w0.z, acc[rr][2]);
        acc[rr][3] = fmaf(a, w0.w, acc[rr][3]);
        acc[rr][4] = fmaf(a, w1.x, acc[rr][4]);
        acc[rr][5] = fmaf(a, w1.y, acc[rr][5]);
        acc[rr][6] = fmaf(a, w1.z, acc[rr][6]);
        acc[rr][7] = fmaf(a, w1.w, acc[rr][7]);
      }
    }
  }
}

// h init + pos copy. grid 4096 x 256 covers 8192*128 exactly.
__global__ void init_kernel(const float* __restrict__ x, const float* __restrict__ ne,
                            float* __restrict__ h, float* __restrict__ pos0,
                            float* __restrict__ posA) {
  int g = blockIdx.x * 256 + threadIdx.x;
  h[g] = ne[g & (H - 1)];
  if (g < 24576) { pos0[g] = x[g]; posA[g] = x[g]; }
}

// Weight prep: transpose + split W2 and Wc1 of each layer into bf16 hi/lo planes.
// dst[(l*2+mat)*16384 + c*128 + k] = split(src[l][k][c]).  grid 512x256.
__global__ void prep_kernel(const float* __restrict__ ew2, const float* __restrict__ cw1,
                            unsigned short* __restrict__ whi, unsigned short* __restrict__ wlo) {
  int idx = blockIdx.x * 256 + threadIdx.x;
  int l = idx >> 15;
  int r = idx & 32767;
  int mat = r >> 14;
  int e = r & 16383;
  int k = e >> 7, c = e & 127;
  const float* src = mat ? cw1 : ew2;
  float w = src[(size_t)l * 16384 + k * 128 + c];
  unsigned short hi = f2bf(w);
  unsigned short lo = f2bf(w - bf2f(hi));
  size_t dst = (size_t)(l * 2 + mat) * 16384 + c * 128 + k;
  whi[dst] = hi;
  wlo[dst] = lo;
}

// Per-node projections: hs = h@W1a, hd = h@W1b + b1, hn = h@Wn1a + bn1
__global__ __launch_bounds__(256) void proj_kernel(
    const float* __restrict__ h, const float* __restrict__ ew1,
    const float* __restrict__ eb1, const float* __restrict__ nw1,
    const float* __restrict__ nb1, float* __restrict__ hs,
    float* __restrict__ hd, float* __restrict__ hn) {
  __shared__ float As[NN * LDP];
  const int tid = threadIdx.x;
  const int rb = blockIdx.x & 127;
  const int wsel = blockIdx.x >> 7;
  const int rowbase = rb * NN;
  for (int f = tid; f < NN * H / 4; f += 256) {
    int row = f >> 5, c4 = (f & 31) << 2;
    *(float4*)(As + row * LDP + c4) = *(const float4*)(h + (size_t)(rowbase + row) * H + c4);
  }
  __syncthreads();
  const float* W; const float* bias; float* out;
  if (wsel == 0)      { W = ew1;          bias = nullptr; out = hs; }
  else if (wsel == 1) { W = ew1 + H * H;  bias = eb1;     out = hd; }
  else                { W = nw1;          bias = nb1;     out = hn; }
  const int tx = tid & 15, ty = tid >> 4;
  const int c0 = tx * 8, r0 = ty * 4;
  float acc[4][8] = {};
  gemm_acc<4>(As, W, acc, r0, c0);
#pragma unroll
  for (int rr = 0; rr < 4; ++rr) {
#pragma unroll
    for (int cc = 0; cc < 8; ++cc) {
      float v = acc[rr][cc] + (bias ? bias[c0 + cc] : 0.0f);
      out[(size_t)(rowbase + r0 + rr) * H + c0 + cc] = v;
    }
  }
}

// Split-bf16 MFMA GEMM. SPLIT_A=true: 3-product AhBh+AlBh+AhBl (A has hi/lo planes).
// SPLIT_A=false: 2-product AhBh+AhBl (A is bf16-only in Ahi).
// Per wave: cols [wave*32, wave*32+32), all 64 rows.
template<bool SPLIT_A>
__device__ __forceinline__ void gemm_mfma(
    const unsigned short* Ahi, const unsigned short* Alo,
    const unsigned short* __restrict__ Bhi, const unsigned short* __restrict__ Blo,
    f4_t (&acc)[4][2], int lane, int wave) {
  const int arow = lane & 15;
  const int kch = (lane >> 4) * 8;
  const int bcol = wave * 32 + (lane & 15);
#pragma unroll
  for (int Kt = 0; Kt < 4; ++Kt) {
    const int k0 = Kt * 32 + kch;
    bf8_t bh0 = *(const bf8_t*)(Bhi + (size_t)bcol * H + k0);
    bf8_t bl0 = *(const bf8_t*)(Blo + (size_t)bcol * H + k0);
    bf8_t bh1 = *(const bf8_t*)(Bhi + (size_t)(bcol + 16) * H + k0);
    bf8_t bl1 = *(const bf8_t*)(Blo + (size_t)(bcol + 16) * H + k0);
#pragma unroll
    for (int Mt = 0; Mt < 4; ++Mt) {
      int row = Mt * 16 + arow;
      int byte = (row * 256 + k0 * 2) ^ ((row & 7) << 4);
      bf8_t ah = *(const bf8_t*)((const char*)Ahi + byte);
      acc[Mt][0] = __builtin_amdgcn_mfma_f32_16x16x32_bf16(ah, bh0, acc[Mt][0], 0, 0, 0);
      acc[Mt][1] = __builtin_amdgcn_mfma_f32_16x16x32_bf16(ah, bh1, acc[Mt][1], 0, 0, 0);
      if (SPLIT_A) {
        bf8_t al = *(const bf8_t*)((const char*)Alo + byte);
        acc[Mt][0] = __builtin_amdgcn_mfma_f32_16x16x32_bf16(al, bh0, acc[Mt][0], 0, 0, 0);
        acc[Mt][1] = __builtin_amdgcn_mfma_f32_16x16x32_bf16(al, bh1, acc[Mt][1], 0, 0, 0);
      }
      acc[Mt][0] = __builtin_amdgcn_mfma_f32_16x16x32_bf16(ah, bl0, acc[Mt][0], 0, 0, 0);
      acc[Mt][1] = __builtin_amdgcn_mfma_f32_16x16x32_bf16(ah, bl1, acc[Mt][1], 0, 0, 0);
    }
  }
}

// One WG (4 waves) per (batch, dst). t1 build -> MFMA edge-MLP2 (+ in-register msg
// reduction, fp32, written direct to global) -> MFMA coord-MLP -> pos update.
// t1 in swizzled bf16 hi/lo planes; m in hi plane only (bf16 feed for GEMM-2).
__global__ __launch_bounds__(256) void edge_kernel(
    const float* __restrict__ hs, const float* __restrict__ hd,
    const float* __restrict__ w1c,
    const unsigned short* __restrict__ w2t_hi, const unsigned short* __restrict__ w2t_lo,
    const unsigned short* __restrict__ wc1t_hi, const unsigned short* __restrict__ wc1t_lo,
    const float* __restrict__ b2, const float* __restrict__ bc1,
    const float* __restrict__ wc2,
    const float* __restrict__ pos_in, float* __restrict__ pos_out,
    float* __restrict__ msg) {
  __shared__ unsigned short Ahi[NN * H];   // 16 KB, XOR-swizzled rows; t1-hi, then m (bf16)
  __shared__ unsigned short Alo[NN * H];   // 16 KB; t1-lo
  __shared__ float posbuf[192];
  __shared__ float relc[3][NN];
  __shared__ float d2s[NN];
  __shared__ float cws[NN];
  __shared__ float hdj[H];
  __shared__ float w1cs[H];
  __shared__ float posjs[3];

  const int tid = threadIdx.x;
  const int lane = tid & 63, wave = tid >> 6;
  const int b = blockIdx.x >> 6;
  const int j = blockIdx.x & 63;
  const int nb = b * NN;

  // Phase A: stage pos, zero cws
  if (tid < 192) posbuf[tid] = pos_in[(size_t)nb * 3 + tid];
  else cws[tid - 192] = 0.0f;
  __syncthreads();
  if (tid < NN) {
    float px = posbuf[tid * 3], py = posbuf[tid * 3 + 1], pz = posbuf[tid * 3 + 2];
    float qx = posbuf[j * 3],   qy = posbuf[j * 3 + 1],   qz = posbuf[j * 3 + 2];
    float rx = px - qx, ry = py - qy, rz = pz - qz;
    relc[0][tid] = rx; relc[1][tid] = ry; relc[2][tid] = rz;
    d2s[tid] = rx * rx + ry * ry + rz * rz;
    if (tid < 3) posjs[tid] = posbuf[j * 3 + tid];
  } else if (tid < 128) {
    int c = tid - 64;
    w1cs[c] = w1c[c];
    w1cs[c + 64] = w1c[c + 64];
  } else {
    hdj[tid - 128] = hd[(size_t)(nb + j) * H + (tid - 128)];
  }
  __syncthreads();

  // Phase B: t1[i][c] = silu(hs[i][c] + hd_j[c] + d2_i*w1c[c]) -> split bf16 planes
  {
    const int c2 = lane * 2;
    float hd0 = hdj[c2], hd1 = hdj[c2 + 1];
    float w10 = w1cs[c2], w11 = w1cs[c2 + 1];
    for (int i = wave; i < NN; i += 4) {
      float2 hv = *(const float2*)(hs + (size_t)(nb + i) * H + c2);
      float d2v = d2s[i];
      float v0 = silu_f(hv.x + hd0 + d2v * w10);
      float v1 = silu_f(hv.y + hd1 + d2v * w11);
      unsigned short h0 = f2bf(v0), h1 = f2bf(v1);
      unsigned short l0 = f2bf(v0 - bf2f(h0)), l1 = f2bf(v1 - bf2f(h1));
      int byte = (i * 256 + c2 * 2) ^ ((i & 7) << 4);
      *(unsigned int*)((char*)Ahi + byte) = (unsigned int)h0 | ((unsigned int)h1 << 16);
      *(unsigned int*)((char*)Alo + byte) = (unsigned int)l0 | ((unsigned int)l1 << 16);
    }
  }
  __syncthreads();

  const int col0 = wave * 32 + (lane & 15);

  // Phase C: m = silu(t1 @ W2 + b2) (MFMA). Epilogue: write m-hi to LDS for GEMM-2,
  // and reduce msg[j][col] = sum_i m[i][col] - m[j][col] entirely in registers (fp32):
  // within each 16-lane column group, {lane>>4} x {Mt} x {r} covers all 64 rows once.
  {
    f4_t acc[4][2];
#pragma unroll
    for (int m = 0; m < 4; ++m) {
      acc[m][0] = (f4_t){0.f, 0.f, 0.f, 0.f};
      acc[m][1] = (f4_t){0.f, 0.f, 0.f, 0.f};
    }
    gemm_mfma<true>(Ahi, Alo, w2t_hi, w2t_lo, acc, lane, wave);
    __syncthreads();   // all A-reads of t1 done before overwrite
    float biasA = b2[col0], biasB = b2[col0 + 16];
    float sA = 0.f, sB = 0.f, sjA = 0.f, sjB = 0.f;
#pragma unroll
    for (int Mt = 0; Mt < 4; ++Mt) {
#pragma unroll
      for (int r = 0; r < 4; ++r) {
        int row = Mt * 16 + (lane >> 4) * 4 + r;
        int rsw = (row & 7) << 4;
        float vA = silu_f(acc[Mt][0][r] + biasA);
        float vB = silu_f(acc[Mt][1][r] + biasB);
        sA += vA; sB += vB;
        if (row == j) { sjA = vA; sjB = vB; }
        *(unsigned short*)((char*)Ahi + ((row * 256 + col0 * 2) ^ rsw)) = f2bf(vA);
        *(unsigned short*)((char*)Ahi + ((row * 256 + (col0 + 16) * 2) ^ rsw)) = f2bf(vB);
      }
    }
    // reduce across the 4 sub-groups (lane bits 4,5) holding the other rows
    sA  += __shfl_xor(sA, 16);  sA  += __shfl_xor(sA, 32);
    sB  += __shfl_xor(sB, 16);  sB  += __shfl_xor(sB, 32);
    sjA += __shfl_xor(sjA, 16); sjA += __shfl_xor(sjA, 32);
    sjB += __shfl_xor(sjB, 16); sjB += __shfl_xor(sjB, 32);
    if (lane < 16) {
      msg[(size_t)(nb + j) * H + col0]      = sA - sjA;  // exclude i==j
      msg[(size_t)(nb + j) * H + col0 + 16] = sB - sjB;
    }
  }
  __syncthreads();

  // Phase D: t2 = silu(m @ Wc1 + bc1); cw[row] = t2 . wc2  (MFMA + reduce)
  {
    f4_t acc2[4][2];
#pragma unroll
    for (int m = 0; m < 4; ++m) {
      acc2[m][0] = (f4_t){0.f, 0.f, 0.f, 0.f};
      acc2[m][1] = (f4_t){0.f, 0.f, 0.f, 0.f};
    }
    gemm_mfma<false>(Ahi, Alo, wc1t_hi, wc1t_lo, acc2, lane, wave);
    float bcA = bc1[col0], bcB = bc1[col0 + 16];
    float wcA = wc2[col0], wcB = wc2[col0 + 16];
#pragma unroll
    for (int Mt = 0; Mt < 4; ++Mt) {
#pragma unroll
      for (int r = 0; r < 4; ++r) {
        int row = Mt * 16 + (lane >> 4) * 4 + r;
        float p = silu_f(acc2[Mt][0][r] + bcA) * wcA
                + silu_f(acc2[Mt][1][r] + bcB) * wcB;
        p += __shfl_xor(p, 8);
        p += __shfl_xor(p, 4);
        p += __shfl_xor(p, 2);
        p += __shfl_xor(p, 1);
        if ((lane & 15) == 0) atomicAdd(&cws[row], p);
      }
    }
  }
  __syncthreads();

  // Phase E: pos update only (msg handled in Phase C). rel[j]=0 makes i==j self-safe.
  if (wave == 0) {
#pragma unroll
    for (int comp = 0; comp < 3; ++comp) {
      float p = relc[comp][lane] * cws[lane];
#pragma unroll
      for (int mk = 32; mk; mk >>= 1) p += __shfl_xor(p, mk);
      if (lane == comp) pos_out[(size_t)(nb + j) * 3 + comp] = posjs[comp] + p;
    }
  }
}

// h += silu(hn + msg@Wn1b) @ Wn2 + bn2 ; row-local, in-place on h. 256 WGs x 32 rows.
__global__ __launch_bounds__(256) void node_kernel(
    const float* __restrict__ msg, const float* __restrict__ hn,
    const float* __restrict__ nw1b, const float* __restrict__ nw2,
    const float* __restrict__ nb2, float* __restrict__ h) {
  __shared__ float As[32 * LDP];
  __shared__ float Bs[32 * LDP];
  __shared__ float Us[32 * LDP];
  const int tid = threadIdx.x;
  const int rowbase = blockIdx.x * 32;
  for (int f = tid; f < 32 * H / 4; f += 256) {
    int row = f >> 5, c4 = (f & 31) << 2;
    *(float4*)(As + row * LDP + c4) = *(const float4*)(msg + (size_t)(rowbase + row) * H + c4);
    *(float4*)(Bs + row * LDP + c4) = *(const float4*)(hn + (size_t)(rowbase + row) * H + c4);
  }
  __syncthreads();
  const int tx = tid & 15, ty = tid >> 4;
  const int c0 = tx * 8, r0 = ty * 2;
  {
    float acc[2][8] = {};
    gemm_acc<2>(As, nw1b, acc, r0, c0);
#pragma unroll
    for (int rr = 0; rr < 2; ++rr)
#pragma unroll
      for (int cc = 0; cc < 8; ++cc)
        Us[(r0 + rr) * LDP + c0 + cc] =
            silu_f(acc[rr][cc] + Bs[(r0 + rr) * LDP + c0 + cc]);
  }
  __syncthreads();
  {
    float acc2[2][8] = {};
    gemm_acc<2>(Us, nw2, acc2, r0, c0);
#pragma unroll
    for (int rr = 0; rr < 2; ++rr)
#pragma unroll
      for (int cc = 0; cc < 8; ++cc) {
        size_t idx = (size_t)(rowbase + r0 + rr) * H + c0 + cc;
        h[idx] += acc2[rr][cc] + nb2[c0 + cc];
      }
  }
}

// dx = pos - pos0, mean-centered over the 64 nodes of each batch, scaled.
__global__ void out_kernel(const float* __restrict__ posF, const float* __restrict__ pos0,
                           const float* __restrict__ scale, float* __restrict__ out) {
  int b = blockIdx.x, i = threadIdx.x;  // 64 threads = 1 wave
  int n = b * NN + i;
  float d0 = posF[n * 3]     - pos0[n * 3];
  float d1 = posF[n * 3 + 1] - pos0[n * 3 + 1];
  float d2v = posF[n * 3 + 2] - pos0[n * 3 + 2];
  float s0 = d0, s1 = d1, s2 = d2v;
  for (int m = 32; m; m >>= 1) {
    s0 += __shfl_xor(s0, m);
    s1 += __shfl_xor(s1, m);
    s2 += __shfl_xor(s2, m);
  }
  const float inv = 1.0f / 64.0f;
  float sc = scale[0];
  out[b * 192 + i * 3]     = (d0 - s0 * inv) * sc;
  out[b * 192 + i * 3 + 1] = (d1 - s1 * inv) * sc;
  out[b * 192 + i * 3 + 2] = (d2v - s2 * inv) * sc;
}

extern "C" void kernel_launch(void* const* d_in, const int* in_sizes, int n_in,
                              void* d_out, int out_size, void* d_ws, size_t ws_size,
                              hipStream_t stream) {
  (void)in_sizes; (void)n_in; (void)out_size; (void)ws_size;
  const float* x   = (const float*)d_in[0];
  const float* ne  = (const float*)d_in[1];
  const float* osc = (const float*)d_in[2];
  const float* ew1 = (const float*)d_in[3];
  const float* eb1 = (const float*)d_in[4];
  const float* ew2 = (const float*)d_in[5];
  const float* eb2 = (const float*)d_in[6];
  const float* cw1 = (const float*)d_in[7];
  const float* cb1 = (const float*)d_in[8];
  const float* cw2 = (const float*)d_in[9];
  const float* nw1 = (const float*)d_in[10];
  const float* nb1 = (const float*)d_in[11];
  const float* nw2 = (const float*)d_in[12];
  const float* nb2 = (const float*)d_in[13];
  // d_in[14] = edge_index: fully-connected structure is generated in-kernel.

  float* ws = (float*)d_ws;
  float* pos0 = ws;                    // 8192*3
  float* posA = pos0 + 24576;
  float* posB = posA + 24576;
  float* h    = posB + 24576;          // 8192*128
  float* hsb  = h   + 1048576;
  float* hdb  = hsb + 1048576;
  float* hnb  = hdb + 1048576;
  float* msgb = hnb + 1048576;
  unsigned short* whi = (unsigned short*)(msgb + 1048576);  // 4L*2mat*16384 ushort
  unsigned short* wlo = whi + 131072;

  init_kernel<<<4096, 256, 0, stream>>>(x, ne, h, pos0, posA);
  prep_kernel<<<512, 256, 0, stream>>>(ew2, cw1, whi, wlo);

  const float* pin[4]  = {posA, posB, posA, posB};
  float*       pout[4] = {posB, posA, posB, posA};

  for (int l = 0; l < 4; ++l) {
    const float* ew1l = ew1 + (size_t)l * 257 * H;
    const unsigned short* w2h = whi + (size_t)l * 2 * 16384;
    const unsigned short* w2l = wlo + (size_t)l * 2 * 16384;
    proj_kernel<<<384, 256, 0, stream>>>(h, ew1l, eb1 + l * H,
                                         nw1 + (size_t)l * 256 * H, nb1 + l * H,
                                         hsb, hdb, hnb);
    edge_kernel<<<8192, 256, 0, stream>>>(hsb, hdb, ew1l + 256 * H,
                                          w2h, w2l, w2h + 16384, w2l + 16384,
                                          eb2 + l * H, cb1 + l * H, cw2 + (size_t)l * H,
                                          pin[l], pout[l], msgb);
    node_kernel<<<256, 256, 0, stream>>>(msgb, hnb,
                                         nw1 + (size_t)l * 256 * H + H * H,
                                         nw2 + (size_t)l * H * H, nb2 + l * H, h);
  }
  out_kernel<<<128, 64, 0, stream>>>(posA, pos0, osc, (float*)d_out);
}

// Round 9
// 1329.549 us; speedup vs baseline: 1.0028x; 1.0028x over previous
//
#include <hip/hip_runtime.h>

#define H 128
#define LDP 132   // fp32 LDS row pitch for proj/node kernels
#define NN 64     // nodes per batch graph

typedef short bf8_t __attribute__((ext_vector_type(8)));   // 8 bf16 = 4 VGPRs (MFMA A/B frag)
typedef float f4_t  __attribute__((ext_vector_type(4)));   // MFMA C/D frag

__device__ __forceinline__ float silu_f(float v) {
  return v * (1.0f / (1.0f + __expf(-v)));
}
// pack 2 fp32 -> 2 bf16 in one inst: D[15:0]=bf16(a), D[31:16]=bf16(b).
// Rounding mode is irrelevant for split-bf16: the lo plane compensates hi.
__device__ __forceinline__ unsigned int cvt_pk_bf16(float a, float b) {
  unsigned int r;
  asm("v_cvt_pk_bf16_f32 %0, %1, %2" : "=v"(r) : "v"(a), "v"(b));
  return r;
}
// fp32 -> bf16 (RNE), scalar (prep kernel only)
__device__ __forceinline__ unsigned short f2bf(float f) {
  unsigned int u = __float_as_uint(f);
  u = (u + 0x7fffu + ((u >> 16) & 1u)) >> 16;
  return (unsigned short)u;
}
__device__ __forceinline__ float bf2f(unsigned short h) {
  return __uint_as_float(((unsigned int)h) << 16);
}

// ---------------- fp32 register-tiled GEMM (proj/node kernels) ----------------
template<int RPT>
__device__ __forceinline__ void gemm_acc(const float* A, const float* __restrict__ Wg,
                                         float (&acc)[RPT][8], int r0, int c0) {
#pragma unroll 4
  for (int k = 0; k < H; k += 4) {
    float4 av[RPT];
#pragma unroll
    for (int rr = 0; rr < RPT; ++rr)
      av[rr] = *(const float4*)(A + (r0 + rr) * LDP + k);
#pragma unroll
    for (int kk = 0; kk < 4; ++kk) {
      const float* wrow = Wg + (k + kk) * H + c0;
      float4 w0 = *(const float4*)(wrow);
      float4 w1 = *(const float4*)(wrow + 4);
#pragma unroll
      for (int rr = 0; rr < RPT; ++rr) {
        float a = (kk == 0) ? av[rr].x : (kk == 1) ? av[rr].y : (kk == 2) ? av[rr].z : av[rr].w;
        acc[rr][0] = fmaf(a, w0.x, acc[rr][0]);
        acc[rr][1] = fmaf(a, w0.y, acc[rr][1]);
        acc[rr][2] = fmaf(a, w0.z, acc[rr][2]);
        acc[rr][3] = fmaf(a, w0.w, acc[rr][3]);
        acc[rr][4] = fmaf(a, w1.x, acc[rr][4]);
        acc[rr][5] = fmaf(a, w1.y, acc[rr][5]);
        acc[rr][6] = fmaf(a, w1.z, acc[rr][6]);
        acc[rr][7] = fmaf(a, w1.w, acc[rr][7]);
      }
    }
  }
}

// h init + pos copy. grid 4096 x 256 covers 8192*128 exactly.
__global__ void init_kernel(const float* __restrict__ x, const float* __restrict__ ne,
                            float* __restrict__ h, float* __restrict__ pos0,
                            float* __restrict__ posA) {
  int g = blockIdx.x * 256 + threadIdx.x;
  h[g] = ne[g & (H - 1)];
  if (g < 24576) { pos0[g] = x[g]; posA[g] = x[g]; }
}

// Weight prep: transpose + split W2 and Wc1 of each layer into bf16 hi/lo planes.
// dst[(l*2+mat)*16384 + c*128 + k] = split(src[l][k][c]).  grid 512x256.
__global__ void prep_kernel(const float* __restrict__ ew2, const float* __restrict__ cw1,
                            unsigned short* __restrict__ whi, unsigned short* __restrict__ wlo) {
  int idx = blockIdx.x * 256 + threadIdx.x;
  int l = idx >> 15;
  int r = idx & 32767;
  int mat = r >> 14;
  int e = r & 16383;
  int k = e >> 7, c = e & 127;
  const float* src = mat ? cw1 : ew2;
  float w = src[(size_t)l * 16384 + k * 128 + c];
  unsigned short hi = f2bf(w);
  unsigned short lo = f2bf(w - bf2f(hi));
  size_t dst = (size_t)(l * 2 + mat) * 16384 + c * 128 + k;
  whi[dst] = hi;
  wlo[dst] = lo;
}

// Per-node projections: hs = h@W1a, hd = h@W1b + b1, hn = h@Wn1a + bn1
__global__ __launch_bounds__(256) void proj_kernel(
    const float* __restrict__ h, const float* __restrict__ ew1,
    const float* __restrict__ eb1, const float* __restrict__ nw1,
    const float* __restrict__ nb1, float* __restrict__ hs,
    float* __restrict__ hd, float* __restrict__ hn) {
  __shared__ float As[NN * LDP];
  const int tid = threadIdx.x;
  const int rb = blockIdx.x & 127;
  const int wsel = blockIdx.x >> 7;
  const int rowbase = rb * NN;
  for (int f = tid; f < NN * H / 4; f += 256) {
    int row = f >> 5, c4 = (f & 31) << 2;
    *(float4*)(As + row * LDP + c4) = *(const float4*)(h + (size_t)(rowbase + row) * H + c4);
  }
  __syncthreads();
  const float* W; const float* bias; float* out;
  if (wsel == 0)      { W = ew1;          bias = nullptr; out = hs; }
  else if (wsel == 1) { W = ew1 + H * H;  bias = eb1;     out = hd; }
  else                { W = nw1;          bias = nb1;     out = hn; }
  const int tx = tid & 15, ty = tid >> 4;
  const int c0 = tx * 8, r0 = ty * 4;
  float acc[4][8] = {};
  gemm_acc<4>(As, W, acc, r0, c0);
#pragma unroll
  for (int rr = 0; rr < 4; ++rr) {
#pragma unroll
    for (int cc = 0; cc < 8; ++cc) {
      float v = acc[rr][cc] + (bias ? bias[c0 + cc] : 0.0f);
      out[(size_t)(rowbase + r0 + rr) * H + c0 + cc] = v;
    }
  }
}

// Split-bf16 MFMA GEMM: 3-product AhBh + AlBh + AhBl (A hi/lo LDS planes,
// B transposed hi/lo global planes). Per wave: cols [wave*32,+32), all 64 rows.
__device__ __forceinline__ void gemm_mfma(
    const unsigned short* Ahi, const unsigned short* Alo,
    const unsigned short* __restrict__ Bhi, const unsigned short* __restrict__ Blo,
    f4_t (&acc)[4][2], int lane, int wave) {
  const int arow = lane & 15;
  const int kch = (lane >> 4) * 8;
  const int bcol = wave * 32 + (lane & 15);
#pragma unroll
  for (int Kt = 0; Kt < 4; ++Kt) {
    const int k0 = Kt * 32 + kch;
    bf8_t bh0 = *(const bf8_t*)(Bhi + (size_t)bcol * H + k0);
    bf8_t bl0 = *(const bf8_t*)(Blo + (size_t)bcol * H + k0);
    bf8_t bh1 = *(const bf8_t*)(Bhi + (size_t)(bcol + 16) * H + k0);
    bf8_t bl1 = *(const bf8_t*)(Blo + (size_t)(bcol + 16) * H + k0);
#pragma unroll
    for (int Mt = 0; Mt < 4; ++Mt) {
      int row = Mt * 16 + arow;
      int byte = (row * 256 + k0 * 2) ^ ((row & 7) << 4);
      bf8_t ah = *(const bf8_t*)((const char*)Ahi + byte);
      bf8_t al = *(const bf8_t*)((const char*)Alo + byte);
      acc[Mt][0] = __builtin_amdgcn_mfma_f32_16x16x32_bf16(ah, bh0, acc[Mt][0], 0, 0, 0);
      acc[Mt][1] = __builtin_amdgcn_mfma_f32_16x16x32_bf16(ah, bh1, acc[Mt][1], 0, 0, 0);
      acc[Mt][0] = __builtin_amdgcn_mfma_f32_16x16x32_bf16(al, bh0, acc[Mt][0], 0, 0, 0);
      acc[Mt][1] = __builtin_amdgcn_mfma_f32_16x16x32_bf16(al, bh1, acc[Mt][1], 0, 0, 0);
      acc[Mt][0] = __builtin_amdgcn_mfma_f32_16x16x32_bf16(ah, bl0, acc[Mt][0], 0, 0, 0);
      acc[Mt][1] = __builtin_amdgcn_mfma_f32_16x16x32_bf16(ah, bl1, acc[Mt][1], 0, 0, 0);
    }
  }
}

// One WG (4 waves) per (batch, dst). t1 build -> MFMA edge-MLP2 (+ in-register msg
// reduction, fp32, direct to global) -> MFMA coord-MLP -> pos update.
// t1 and m both in swizzled bf16 hi/lo LDS planes (3-product both GEMMs).
__global__ __launch_bounds__(256) void edge_kernel(
    const float* __restrict__ hs, const float* __restrict__ hd,
    const float* __restrict__ w1c,
    const unsigned short* __restrict__ w2t_hi, const unsigned short* __restrict__ w2t_lo,
    const unsigned short* __restrict__ wc1t_hi, const unsigned short* __restrict__ wc1t_lo,
    const float* __restrict__ b2, const float* __restrict__ bc1,
    const float* __restrict__ wc2,
    const float* __restrict__ pos_in, float* __restrict__ pos_out,
    float* __restrict__ msg) {
  __shared__ unsigned short Ahi[NN * H];   // 16 KB, XOR-swizzled rows; t1-hi then m-hi
  __shared__ unsigned short Alo[NN * H];   // 16 KB; t1-lo then m-lo
  __shared__ float posbuf[192];
  __shared__ float relc[3][NN];
  __shared__ float d2s[NN];
  __shared__ float cws4[4 * NN];           // per-wave cw partials (no atomics)
  __shared__ float hdj[H];
  __shared__ float w1cs[H];
  __shared__ float posjs[3];

  const int tid = threadIdx.x;
  const int lane = tid & 63, wave = tid >> 6;
  const int b = blockIdx.x >> 6;
  const int j = blockIdx.x & 63;
  const int nb = b * NN;

  // Phase A: stage pos
  if (tid < 192) posbuf[tid] = pos_in[(size_t)nb * 3 + tid];
  __syncthreads();
  if (tid < NN) {
    float px = posbuf[tid * 3], py = posbuf[tid * 3 + 1], pz = posbuf[tid * 3 + 2];
    float qx = posbuf[j * 3],   qy = posbuf[j * 3 + 1],   qz = posbuf[j * 3 + 2];
    float rx = px - qx, ry = py - qy, rz = pz - qz;
    relc[0][tid] = rx; relc[1][tid] = ry; relc[2][tid] = rz;
    d2s[tid] = rx * rx + ry * ry + rz * rz;
    if (tid < 3) posjs[tid] = posbuf[j * 3 + tid];
  } else if (tid < 128) {
    int c = tid - 64;
    w1cs[c] = w1c[c];
    w1cs[c + 64] = w1c[c + 64];
  } else {
    hdj[tid - 128] = hd[(size_t)(nb + j) * H + (tid - 128)];
  }
  __syncthreads();

  // Phase B: t1[i][c] = silu(hs[i][c] + hd_j[c] + d2_i*w1c[c]) -> split bf16 planes
  {
    const int c2 = lane * 2;
    float hd0 = hdj[c2], hd1 = hdj[c2 + 1];
    float w10 = w1cs[c2], w11 = w1cs[c2 + 1];
    for (int i = wave; i < NN; i += 4) {
      float2 hv = *(const float2*)(hs + (size_t)(nb + i) * H + c2);
      float d2v = d2s[i];
      float v0 = silu_f(hv.x + hd0 + d2v * w10);
      float v1 = silu_f(hv.y + hd1 + d2v * w11);
      unsigned int ph = cvt_pk_bf16(v0, v1);            // lo16=bf(v0), hi16=bf(v1)
      float r0 = v0 - __uint_as_float(ph << 16);
      float r1 = v1 - __uint_as_float(ph & 0xFFFF0000u);
      unsigned int pl = cvt_pk_bf16(r0, r1);
      int byte = (i * 256 + c2 * 2) ^ ((i & 7) << 4);
      *(unsigned int*)((char*)Ahi + byte) = ph;
      *(unsigned int*)((char*)Alo + byte) = pl;
    }
  }
  __syncthreads();

  const int col0 = wave * 32 + (lane & 15);

  // Phase C: m = silu(t1 @ W2 + b2) (MFMA). Epilogue: split m into hi/lo planes and
  // reduce msg[j][col] = sum_i m[i][col] - m[j][col] in registers (fp32): within each
  // 16-lane column group, {lane>>4} x {Mt} x {r} covers all 64 rows exactly once.
  {
    f4_t acc[4][2];
#pragma unroll
    for (int m = 0; m < 4; ++m) {
      acc[m][0] = (f4_t){0.f, 0.f, 0.f, 0.f};
      acc[m][1] = (f4_t){0.f, 0.f, 0.f, 0.f};
    }
    gemm_mfma(Ahi, Alo, w2t_hi, w2t_lo, acc, lane, wave);
    __syncthreads();   // all A-reads of t1 done before overwrite
    float biasA = b2[col0], biasB = b2[col0 + 16];
    float sA = 0.f, sB = 0.f, sjA = 0.f, sjB = 0.f;
#pragma unroll
    for (int Mt = 0; Mt < 4; ++Mt) {
#pragma unroll
      for (int r = 0; r < 4; ++r) {
        int row = Mt * 16 + (lane >> 4) * 4 + r;
        int rsw = (row & 7) << 4;
        float vA = silu_f(acc[Mt][0][r] + biasA);
        float vB = silu_f(acc[Mt][1][r] + biasB);
        sA += vA; sB += vB;
        if (row == j) { sjA = vA; sjB = vB; }
        unsigned int ph = cvt_pk_bf16(vA, vB);          // lo16=bf(vA), hi16=bf(vB)
        float rA = vA - __uint_as_float(ph << 16);
        float rB = vB - __uint_as_float(ph & 0xFFFF0000u);
        unsigned int pl = cvt_pk_bf16(rA, rB);
        int byA = (row * 256 + col0 * 2) ^ rsw;
        int byB = (row * 256 + (col0 + 16) * 2) ^ rsw;
        *(unsigned short*)((char*)Ahi + byA) = (unsigned short)ph;
        *(unsigned short*)((char*)Ahi + byB) = (unsigned short)(ph >> 16);
        *(unsigned short*)((char*)Alo + byA) = (unsigned short)pl;
        *(unsigned short*)((char*)Alo + byB) = (unsigned short)(pl >> 16);
      }
    }
    // reduce across the 4 sub-groups (lane bits 4,5) holding the other rows
    sA  += __shfl_xor(sA, 16);  sA  += __shfl_xor(sA, 32);
    sB  += __shfl_xor(sB, 16);  sB  += __shfl_xor(sB, 32);
    sjA += __shfl_xor(sjA, 16); sjA += __shfl_xor(sjA, 32);
    sjB += __shfl_xor(sjB, 16); sjB += __shfl_xor(sjB, 32);
    if (lane < 16) {
      msg[(size_t)(nb + j) * H + col0]      = sA - sjA;  // exclude i==j
      msg[(size_t)(nb + j) * H + col0 + 16] = sB - sjB;
    }
  }
  __syncthreads();

  // Phase D: t2 = silu(m @ Wc1 + bc1); cw partials per wave (each wave covers all
  // 64 rows over its 32 cols; no atomics — cws4[wave][row] written exactly once).
  {
    f4_t acc2[4][2];
#pragma unroll
    for (int m = 0; m < 4; ++m) {
      acc2[m][0] = (f4_t){0.f, 0.f, 0.f, 0.f};
      acc2[m][1] = (f4_t){0.f, 0.f, 0.f, 0.f};
    }
    gemm_mfma(Ahi, Alo, wc1t_hi, wc1t_lo, acc2, lane, wave);
    float bcA = bc1[col0], bcB = bc1[col0 + 16];
    float wcA = wc2[col0], wcB = wc2[col0 + 16];
#pragma unroll
    for (int Mt = 0; Mt < 4; ++Mt) {
#pragma unroll
      for (int r = 0; r < 4; ++r) {
        int row = Mt * 16 + (lane >> 4) * 4 + r;
        float p = silu_f(acc2[Mt][0][r] + bcA) * wcA
                + silu_f(acc2[Mt][1][r] + bcB) * wcB;
        p += __shfl_xor(p, 8);
        p += __shfl_xor(p, 4);
        p += __shfl_xor(p, 2);
        p += __shfl_xor(p, 1);
        if ((lane & 15) == 0) cws4[wave * NN + row] = p;
      }
    }
  }
  __syncthreads();

  // Phase E: pos update (msg handled in Phase C). rel[j]=0 makes i==j self-safe.
  if (wave == 0) {
    float cw = cws4[lane] + cws4[NN + lane] + cws4[2 * NN + lane] + cws4[3 * NN + lane];
#pragma unroll
    for (int comp = 0; comp < 3; ++comp) {
      float p = relc[comp][lane] * cw;
#pragma unroll
      for (int mk = 32; mk; mk >>= 1) p += __shfl_xor(p, mk);
      if (lane == comp) pos_out[(size_t)(nb + j) * 3 + comp] = posjs[comp] + p;
    }
  }
}

// h += silu(hn + msg@Wn1b) @ Wn2 + bn2 ; row-local, in-place on h. 256 WGs x 32 rows.
__global__ __launch_bounds__(256) void node_kernel(
    const float* __restrict__ msg, const float* __restrict__ hn,
    const float* __restrict__ nw1b, const float* __restrict__ nw2,
    const float* __restrict__ nb2, float* __restrict__ h) {
  __shared__ float As[32 * LDP];
  __shared__ float Bs[32 * LDP];
  __shared__ float Us[32 * LDP];
  const int tid = threadIdx.x;
  const int rowbase = blockIdx.x * 32;
  for (int f = tid; f < 32 * H / 4; f += 256) {
    int row = f >> 5, c4 = (f & 31) << 2;
    *(float4*)(As + row * LDP + c4) = *(const float4*)(msg + (size_t)(rowbase + row) * H + c4);
    *(float4*)(Bs + row * LDP + c4) = *(const float4*)(hn + (size_t)(rowbase + row) * H + c4);
  }
  __syncthreads();
  const int tx = tid & 15, ty = tid >> 4;
  const int c0 = tx * 8, r0 = ty * 2;
  {
    float acc[2][8] = {};
    gemm_acc<2>(As, nw1b, acc, r0, c0);
#pragma unroll
    for (int rr = 0; rr < 2; ++rr)
#pragma unroll
      for (int cc = 0; cc < 8; ++cc)
        Us[(r0 + rr) * LDP + c0 + cc] =
            silu_f(acc[rr][cc] + Bs[(r0 + rr) * LDP + c0 + cc]);
  }
  __syncthreads();
  {
    float acc2[2][8] = {};
    gemm_acc<2>(Us, nw2, acc2, r0, c0);
#pragma unroll
    for (int rr = 0; rr < 2; ++rr)
#pragma unroll
      for (int cc = 0; cc < 8; ++cc) {
        size_t idx = (size_t)(rowbase + r0 + rr) * H + c0 + cc;
        h[idx] += acc2[rr][cc] + nb2[c0 + cc];
      }
  }
}

// dx = pos - pos0, mean-centered over the 64 nodes of each batch, scaled.
__global__ void out_kernel(const float* __restrict__ posF, const float* __restrict__ pos0,
                           const float* __restrict__ scale, float* __restrict__ out) {
  int b = blockIdx.x, i = threadIdx.x;  // 64 threads = 1 wave
  int n = b * NN + i;
  float d0 = posF[n * 3]     - pos0[n * 3];
  float d1 = posF[n * 3 + 1] - pos0[n * 3 + 1];
  float d2v = posF[n * 3 + 2] - pos0[n * 3 + 2];
  float s0 = d0, s1 = d1, s2 = d2v;
  for (int m = 32; m; m >>= 1) {
    s0 += __shfl_xor(s0, m);
    s1 += __shfl_xor(s1, m);
    s2 += __shfl_xor(s2, m);
  }
  const float inv = 1.0f / 64.0f;
  float sc = scale[0];
  out[b * 192 + i * 3]     = (d0 - s0 * inv) * sc;
  out[b * 192 + i * 3 + 1] = (d1 - s1 * inv) * sc;
  out[b * 192 + i * 3 + 2] = (d2v - s2 * inv) * sc;
}

extern "C" void kernel_launch(void* const* d_in, const int* in_sizes, int n_in,
                              void* d_out, int out_size, void* d_ws, size_t ws_size,
                              hipStream_t stream) {
  (void)in_sizes; (void)n_in; (void)out_size; (void)ws_size;
  const float* x   = (const float*)d_in[0];
  const float* ne  = (const float*)d_in[1];
  const float* osc = (const float*)d_in[2];
  const float* ew1 = (const float*)d_in[3];
  const float* eb1 = (const float*)d_in[4];
  const float* ew2 = (const float*)d_in[5];
  const float* eb2 = (const float*)d_in[6];
  const float* cw1 = (const float*)d_in[7];
  const float* cb1 = (const float*)d_in[8];
  const float* cw2 = (const float*)d_in[9];
  const float* nw1 = (const float*)d_in[10];
  const float* nb1 = (const float*)d_in[11];
  const float* nw2 = (const float*)d_in[12];
  const float* nb2 = (const float*)d_in[13];
  // d_in[14] = edge_index: fully-connected structure is generated in-kernel.

  float* ws = (float*)d_ws;
  float* pos0 = ws;                    // 8192*3
  float* posA = pos0 + 24576;
  float* posB = posA + 24576;
  float* h    = posB + 24576;          // 8192*128
  float* hsb  = h   + 1048576;
  float* hdb  = hsb + 1048576;
  float* hnb  = hdb + 1048576;
  float* msgb = hnb + 1048576;
  unsigned short* whi = (unsigned short*)(msgb + 1048576);  // 4L*2mat*16384 ushort
  unsigned short* wlo = whi + 131072;

  init_kernel<<<4096, 256, 0, stream>>>(x, ne, h, pos0, posA);
  prep_kernel<<<512, 256, 0, stream>>>(ew2, cw1, whi, wlo);

  const float* pin[4]  = {posA, posB, posA, posB};
  float*       pout[4] = {posB, posA, posB, posA};

  for (int l = 0; l < 4; ++l) {
    const float* ew1l = ew1 + (size_t)l * 257 * H;
    const unsigned short* w2h = whi + (size_t)l * 2 * 16384;
    const unsigned short* w2l = wlo + (size_t)l * 2 * 16384;
    proj_kernel<<<384, 256, 0, stream>>>(h, ew1l, eb1 + l * H,
                                         nw1 + (size_t)l * 256 * H, nb1 + l * H,
                                         hsb, hdb, hnb);
    edge_kernel<<<8192, 256, 0, stream>>>(hsb, hdb, ew1l + 256 * H,
                                          w2h, w2l, w2h + 16384, w2l + 16384,
                                          eb2 + l * H, cb1 + l * H, cw2 + (size_t)l * H,
                                          pin[l], pout[l], msgb);
    node_kernel<<<256, 256, 0, stream>>>(msgb, hnb,
                                         nw1 + (size_t)l * 256 * H + H * H,
                                         nw2 + (size_t)l * H * H, nb2 + l * H, h);
  }
  out_kernel<<<128, 64, 0, stream>>>(posA, pos0, osc, (float*)d_out);
}